// Round 3
// baseline (242.916 us; speedup 1.0000x reference)
//
#include <hip/hip_runtime.h>
#include <hip/hip_bf16.h>
#include <math.h>

// Problem constants: B=4, L=2048, D=1024, H=16, hd=64
// M = B*L = 8192, QKV N = 3072, proj N = 1024, K = 1024

typedef unsigned short u16;
typedef __attribute__((ext_vector_type(8))) short bf8;   // 8 bf16 = 4 VGPR (MFMA A/B frag, K=32)
typedef __attribute__((ext_vector_type(4))) short bf4;   // 4 bf16 = 2 VGPR (MFMA A/B frag, K=16)
typedef __attribute__((ext_vector_type(4))) float f4;    // MFMA C/D frag

__device__ __forceinline__ u16 f2bf(float f) {
  unsigned int u = __float_as_uint(f);
  unsigned int r = (u + 0x7fffu + ((u >> 16) & 1u)) >> 16;
  return (u16)r;
}

__device__ __forceinline__ f4 mfma16(bf8 a, bf8 b, f4 c) {
  return __builtin_amdgcn_mfma_f32_16x16x32_bf16(a, b, c, 0, 0, 0);
}

__device__ __forceinline__ f4 mfma16x16(bf4 a, bf4 b, f4 c) {
#if __has_builtin(__builtin_amdgcn_mfma_f32_16x16x16bf16_1k)
  return __builtin_amdgcn_mfma_f32_16x16x16bf16_1k(a, b, c, 0, 0, 0);
#elif __has_builtin(__builtin_amdgcn_mfma_f32_16x16x16_bf16)
  return __builtin_amdgcn_mfma_f32_16x16x16_bf16(a, b, c, 0, 0, 0);
#else
  f4 d;
  asm volatile("v_mfma_f32_16x16x16_bf16 %0, %1, %2, %3"
               : "=v"(d) : "v"(a), "v"(b), "v"(c));
  return d;
#endif
}

__device__ __forceinline__ float fexp2(float x) {
#if __has_builtin(__builtin_amdgcn_exp2f)
  return __builtin_amdgcn_exp2f(x);
#else
  return exp2f(x);
#endif
}

__device__ __forceinline__ void async_copy16(const void* gsrc, void* ldst) {
  __builtin_amdgcn_global_load_lds(
      (__attribute__((address_space(1))) void*)gsrc,
      (__attribute__((address_space(3))) void*)ldst,
      16, 0, 0);
}

// ---------------- prep kernels ----------------

__global__ __launch_bounds__(256) void convert_bf16_k(const float* __restrict__ in,
                                                      u16* __restrict__ out, int n4) {
  int i = blockIdx.x * blockDim.x + threadIdx.x;
  if (i < n4) {
    float4 v = ((const float4*)in)[i];
    ushort4 o;
    o.x = f2bf(v.x); o.y = f2bf(v.y); o.z = f2bf(v.z); o.w = f2bf(v.w);
    ((ushort4*)out)[i] = o;
  }
}

// in [K][N] f32 row-major -> out [N][K] bf16 row-major (B^T layout). 64x64 tiles.
__global__ __launch_bounds__(256) void transpose_bf16_k(const float* __restrict__ in,
                                                        u16* __restrict__ out, int K, int N) {
  __shared__ float t[64][65];
  int k0 = blockIdx.x * 64;
  int n0 = blockIdx.y * 64;
  int tx = threadIdx.x & 63, ty = threadIdx.x >> 6;  // 4 rows per pass
  for (int i = 0; i < 16; i++) {
    int r = ty + i * 4;
    t[r][tx] = in[(size_t)(k0 + r) * N + n0 + tx];
  }
  __syncthreads();
  for (int i = 0; i < 16; i++) {
    int r = ty + i * 4;
    out[(size_t)(n0 + r) * K + k0 + tx] = f2bf(t[tx][r]);
  }
}

// cos/sin tables [2048][32] f32
__global__ __launch_bounds__(256) void rope_tables_k(float* __restrict__ cosT,
                                                     float* __restrict__ sinT) {
  int i = blockIdx.x * blockDim.x + threadIdx.x;  // 65536
  int l = i >> 5, j = i & 31;
  float inv = powf(10000.0f, -(float)j / 32.0f);
  float f = (float)l * inv;
  cosT[i] = cosf(f);
  sinT[i] = sinf(f);
}

// ---------------- deep-pipelined GEMM (A[M][K]bf16 x Bt[N][K]bf16) ----------------
// BM=256, BN in {256,128}, BK=32. 512 threads = 8 waves (2 M x 4 N); per-wave
// output 128 x (BN/4). 4 LDS buffers, pipeline depth 3: stage tile t+3 while
// computing tile t; boundary wait is counted vmcnt(2*LOADS) - never drain-0 in
// the main loop (T3+T4). Per tile: 2 phases x 16(8) MFMA with setprio (T5).
// LDS layout [row][32k] with col16 ^= ((row>>1)&3) XOR swizzle applied to both
// the pre-swizzled global source (global_load_lds writes linearly) and ds_read.
// EPI==0: out f32 += bias. EPI==1: fused bias+RoPE -> Qb/Kb [bh][l][64], Vt [bh][64][l].

template <int BN, int EPI>
__global__ __launch_bounds__(512, 2) void gemm8p(
    const u16* __restrict__ A, const u16* __restrict__ Bt, const float* __restrict__ bias,
    float* __restrict__ outF,
    u16* __restrict__ Qb, u16* __restrict__ Kb, u16* __restrict__ Vt,
    const float* __restrict__ cosT, const float* __restrict__ sinT,
    int M, int N, int K) {
  constexpr int BM = 256;
  constexpr int A_U16 = BM * 32;              // 8192 u16 = 16 KB
  constexpr int B_U16 = BN * 32;
  constexpr int TILE_U16 = A_U16 + B_U16;
  constexpr int LOADS = (TILE_U16 * 2) / (512 * 16);  // 4 (BN=256) or 3 (BN=128)
  constexpr int NF = BN / 64;                 // per-wave N frags: 4 or 2
  __shared__ __attribute__((aligned(16))) u16 lds[4][TILE_U16];

  const int tid = threadIdx.x;
  const int lane = tid & 63, wid = tid >> 6;
  const int nbn = N / BN;
  const int cpx = gridDim.x >> 3;             // grid % 8 == 0 by construction
  const int bid = ((int)blockIdx.x % 8) * cpx + ((int)blockIdx.x >> 3);
  const int bm = bid / nbn, bn = bid % nbn;
  const int m0 = bm * BM, n0 = bn * BN;
  const int wm = wid >> 2, wn = wid & 3;      // 2 x 4 waves
  const int g = lane >> 4, c0 = lane & 15;
  const int NT = K >> 5;                      // 32 K-tiles

  auto stage = [&](int t, int buf, int lo, int hi) {
#pragma unroll
    for (int i = lo; i < hi; ++i) {
      int off = i * 8192 + tid * 16;          // byte offset within tile (linear LDS dest)
      char* dst = (char*)lds[buf] + off;
      int row, col16;
      const u16* gbase;
      if (off < A_U16 * 2) {
        row = off >> 6; col16 = (off >> 4) & 3;
        gbase = A + (size_t)(m0 + row) * K;
      } else {
        int boff = off - A_U16 * 2;
        row = boff >> 6; col16 = (boff >> 4) & 3;
        gbase = Bt + (size_t)(n0 + row) * K;
      }
      int cs = col16 ^ ((row >> 1) & 3);      // pre-swizzle SOURCE (involution)
      async_copy16((const char*)(gbase + (t << 5)) + cs * 16, dst);
    }
  };
  auto rdA = [&](const u16* bufA, int mf) -> bf8 {
    int row = wm * 128 + mf * 16 + c0;
    int cs = g ^ ((row >> 1) & 3);
    return *(const bf8*)((const char*)bufA + row * 64 + cs * 16);
  };
  auto rdB = [&](const u16* bufB, int nf) -> bf8 {
    int row = wn * (BN / 4) + nf * 16 + c0;
    int cs = g ^ ((row >> 1) & 3);
    return *(const bf8*)((const char*)bufB + row * 64 + cs * 16);
  };

  f4 acc[8][NF];
#pragma unroll
  for (int i = 0; i < 8; i++)
#pragma unroll
    for (int j = 0; j < NF; j++) acc[i][j] = (f4)0.0f;

  // prologue: 3 tiles in flight, counted wait for tile 0
  stage(0, 0, 0, LOADS);
  stage(1, 1, 0, LOADS);
  stage(2, 2, 0, LOADS);
  if constexpr (LOADS == 4) asm volatile("s_waitcnt vmcnt(8)" ::: "memory");
  else                      asm volatile("s_waitcnt vmcnt(6)" ::: "memory");
  __builtin_amdgcn_s_barrier();

  for (int t = 0; t < NT; ++t) {
    const u16* bufA = lds[t & 3];
    const u16* bufB = bufA + A_U16;
    const bool pf = (t + 3 < NT);

    // ---- phase 0: stage half, read B + A(0-3), MFMA quadrant ----
    if (pf) stage(t + 3, (t + 3) & 3, 0, LOADS / 2);
    bf8 bfr[NF], afr[4];
#pragma unroll
    for (int nf = 0; nf < NF; nf++) bfr[nf] = rdB(bufB, nf);
#pragma unroll
    for (int mf = 0; mf < 4; mf++) afr[mf] = rdA(bufA, mf);
    __builtin_amdgcn_s_setprio(1);
#pragma unroll
    for (int mf = 0; mf < 4; mf++)
#pragma unroll
      for (int nf = 0; nf < NF; nf++)
        acc[mf][nf] = mfma16(afr[mf], bfr[nf], acc[mf][nf]);
    __builtin_amdgcn_s_setprio(0);
    __builtin_amdgcn_s_barrier();

    // ---- phase 1: stage rest, read A(4-7), MFMA quadrant ----
    if (pf) stage(t + 3, (t + 3) & 3, LOADS / 2, LOADS);
#pragma unroll
    for (int mf = 0; mf < 4; mf++) afr[mf] = rdA(bufA, mf + 4);
    __builtin_amdgcn_s_setprio(1);
#pragma unroll
    for (int mf = 0; mf < 4; mf++)
#pragma unroll
      for (int nf = 0; nf < NF; nf++)
        acc[mf + 4][nf] = mfma16(afr[mf], bfr[nf], acc[mf + 4][nf]);
    __builtin_amdgcn_s_setprio(0);

    // ---- boundary: counted vmcnt so tile t+1 is resident; never 0 mid-loop ----
    if (t + 3 < NT) {
      if constexpr (LOADS == 4) asm volatile("s_waitcnt vmcnt(8)" ::: "memory");
      else                      asm volatile("s_waitcnt vmcnt(6)" ::: "memory");
    } else if (t + 2 < NT) {
      if constexpr (LOADS == 4) asm volatile("s_waitcnt vmcnt(4)" ::: "memory");
      else                      asm volatile("s_waitcnt vmcnt(3)" ::: "memory");
    } else if (t + 1 < NT) {
      asm volatile("s_waitcnt vmcnt(0)" ::: "memory");
    }
    if (t + 1 < NT) __builtin_amdgcn_s_barrier();
  }

  // ---- epilogue ----
  if (EPI == 0) {
#pragma unroll
    for (int nf = 0; nf < NF; nf++) {
      int col = n0 + wn * (BN / 4) + nf * 16 + c0;
      float bv = bias[col];
#pragma unroll
      for (int mf = 0; mf < 8; mf++) {
        int rowb = m0 + wm * 128 + mf * 16 + g * 4;
#pragma unroll
        for (int r = 0; r < 4; r++)
          outF[(size_t)(rowb + r) * N + col] = acc[mf][nf][r] + bv;
      }
    }
  } else {
#pragma unroll
    for (int nf = 0; nf < NF; nf++) {
      int col = n0 + wn * 64 + nf * 16 + c0;
      int sec = col >> 10;          // 0=q 1=k 2=v
      int hc = col & 1023;
      int h = hc >> 6, d = hc & 63;
      float bv = bias[col];
      int pcol = n0 + wn * 64 + (nf ^ 2) * 16 + c0;  // RoPE partner col (d +/- 32), same lane
      float pbv = bias[pcol];
#pragma unroll
      for (int mf = 0; mf < 8; mf++) {
        int rowb = m0 + wm * 128 + mf * 16 + g * 4;
#pragma unroll
        for (int r = 0; r < 4; r++) {
          int row = rowb + r;
          int bb = row >> 11, l = row & 2047;
          int bh = bb * 16 + h;
          float v = acc[mf][nf][r] + bv;
          if (sec == 2) {
            Vt[((size_t)bh * 64 + d) * 2048 + l] = f2bf(v);  // V stored transposed [bh][d][l]
          } else {
            int dm = d & 31;
            float cz = cosT[l * 32 + dm], sz = sinT[l * 32 + dm];
            float pv = acc[mf][nf ^ 2][r] + pbv;
            float o = (d < 32) ? (v * cz - pv * sz) : (v * cz + pv * sz);
            u16* dst = (sec == 0) ? Qb : Kb;
            dst[((size_t)bh * 2048 + l) * 64 + d] = f2bf(o);
          }
        }
      }
    }
  }
}

// ---------------- flash attention (swapped-operand, balanced pairs) ----------------
// 512 blocks = 64 bh x 8 q-tile-pairs; block handles q-tiles (pi) and (15-pi): exactly
// 34 KV-tiles of work each -> perfectly balanced, all blocks co-resident (2/CU).
// 4 waves x 32 q rows. KV tile 64. S^T = mfma(K, Q): lane owns one q-row (q=col=c0);
// softmax is lane-local + 2 shfl_xor; P is *already* the 16x16x16 PV B-fragment
// (k = 4g + r) -> no LDS round-trip, no cross-lane P movement.
// K/V double-buffered in LDS via global_load_lds with XOR-swizzled source.
__global__ __launch_bounds__(256, 2) void attn_fwd(
    const u16* __restrict__ Qb, const u16* __restrict__ Kb, const u16* __restrict__ Vt,
    u16* __restrict__ attnOut) {
  __shared__ __attribute__((aligned(16))) u16 kT[2][64 * 64];
  __shared__ __attribute__((aligned(16))) u16 vT[2][64 * 64];
  const int tid = threadIdx.x, lane = tid & 63, wid = tid >> 6;
  // XCD swizzle: 8 blocks sharing one bh land on one XCD (K/V 4MB/XCD = L2-fit)
  const int pblk = blockIdx.x;                 // nwg = 512
  const int lblk = ((pblk & 7) << 6) | (pblk >> 3);
  const int bh = lblk >> 3, pi = lblk & 7;
  const int bb = bh >> 4, h = bh & 15;
  const u16* Qp = Qb + (size_t)bh * 2048 * 64;
  const u16* Kp = Kb + (size_t)bh * 2048 * 64;
  const u16* Vp = Vt + (size_t)bh * 64 * 2048;   // [64 d][2048 l]
  const int g = lane >> 4, c0 = lane & 15;
  const float sc = 0.125f * 1.4426950408889634f;  // scale * log2(e)

  auto stage = [&](int kt, int buf) {
    int kv0 = kt * 64;
    for (int i = 0; i < 2; i++) {
      int chunk = i * 4 + wid;
      int p = chunk * 1024 + lane * 16;
      int row = p >> 7, pb = p & 127;
      int lb = pb ^ ((row & 7) << 4);
      async_copy16((const char*)(Kp + (size_t)(kv0 + row) * 64) + lb,
                   (char*)kT[buf] + chunk * 1024);
      async_copy16((const char*)(Vp + (size_t)row * 2048 + kv0) + lb,
                   (char*)vT[buf] + chunk * 1024);
    }
  };

  for (int seg = 0; seg < 2; ++seg) {
    const int qt = seg ? (15 - pi) : pi;
    const int q0 = qt << 7;
    const int qw = q0 + wid * 32;

    // Q B-fragments hoisted (n = q = c0, k = d contiguous)
    bf8 qfr[2][2];
    for (int qf = 0; qf < 2; qf++)
      for (int ks = 0; ks < 2; ks++)
        qfr[qf][ks] = *(const bf8*)((const char*)Qp +
                                    (size_t)(qw + qf * 16 + c0) * 128 + ks * 64 + g * 16);

    f4 accO[2][4];
    for (int i = 0; i < 2; i++)
      for (int j = 0; j < 4; j++) accO[i][j] = (f4)0.0f;
    float mrun[2] = {-INFINITY, -INFINITY}, lrun[2] = {0.f, 0.f};

    const int nkt = (q0 >> 6) + 2;
    stage(0, 0);
    __syncthreads();

    for (int kt = 0; kt < nkt; ++kt) {
      const int cur = kt & 1;
      if (kt + 1 < nkt) stage(kt + 1, cur ^ 1);
      const char* kbuf = (const char*)kT[cur];
      const char* vbuf = (const char*)vT[cur];
      const int kv0 = kt * 64;

      // S^T = K Q^T  (m = kv, n = q)
      f4 s[2][4];
      for (int i = 0; i < 2; i++)
        for (int j = 0; j < 4; j++) s[i][j] = (f4)0.0f;
      bf8 kf[4][2];
      for (int ks = 0; ks < 2; ks++) {
        int cb = ks * 64 + g * 16;
        for (int kvf = 0; kvf < 4; kvf++) {
          int row = kvf * 16 + c0;
          kf[kvf][ks] = *(const bf8*)(kbuf + (row << 7) + (cb ^ ((row & 7) << 4)));
        }
      }
      for (int ks = 0; ks < 2; ks++)
        for (int kvf = 0; kvf < 4; kvf++)
          for (int qf = 0; qf < 2; qf++)
            s[qf][kvf] = mfma16(kf[kvf][ks], qfr[qf][ks], s[qf][kvf]);

      // scale to log2 domain + causal mask (q = qw+qf*16+c0, kv = kv0+kvf*16+4g+r)
      for (int qf = 0; qf < 2; qf++) {
        int q = qw + qf * 16 + c0;
        for (int kvf = 0; kvf < 4; kvf++)
          for (int r = 0; r < 4; r++) {
            int kv = kv0 + kvf * 16 + 4 * g + r;
            float v = s[qf][kvf][r] * sc;
            s[qf][kvf][r] = (kv > q) ? -INFINITY : v;
          }
      }

      // online softmax: lane-local reduce + 2 shfl_xor across the 4 g-groups
      bf4 pfrag[2][4];
      float pc[2];
      for (int qf = 0; qf < 2; qf++) {
        float mx = s[qf][0][0];
        for (int kvf = 0; kvf < 4; kvf++)
          for (int r = 0; r < 4; r++) mx = fmaxf(mx, s[qf][kvf][r]);
        mx = fmaxf(mx, __shfl_xor(mx, 16));
        mx = fmaxf(mx, __shfl_xor(mx, 32));
        float mn = fmaxf(mrun[qf], mx);
        pc[qf] = fexp2(mrun[qf] - mn);
        float ls = 0.f;
        for (int kvf = 0; kvf < 4; kvf++) {
          bf4 pf;
          for (int r = 0; r < 4; r++) {
            float pv = fexp2(s[qf][kvf][r] - mn);
            ls += pv;
            pf[r] = (short)f2bf(pv);
          }
          pfrag[qf][kvf] = pf;
        }
        ls += __shfl_xor(ls, 16);
        ls += __shfl_xor(ls, 32);
        lrun[qf] = lrun[qf] * pc[qf] + ls;
        mrun[qf] = mn;
      }

      // rescale O
      for (int qf = 0; qf < 2; qf++)
        for (int df = 0; df < 4; df++)
          for (int r = 0; r < 4; r++) accO[qf][df][r] *= pc[qf];

      // O^T += V^T P^T  via 16x16x16 (A = V^T rows d, B = P fragment direct from regs)
      for (int kvf = 0; kvf < 4; kvf++) {
        bf4 vf[4];
        int cb = kvf * 32 + g * 8;
        for (int df = 0; df < 4; df++) {
          int row = df * 16 + c0;
          vf[df] = *(const bf4*)(vbuf + (row << 7) + (cb ^ ((row & 7) << 4)));
        }
        for (int df = 0; df < 4; df++)
          for (int qf = 0; qf < 2; qf++)
            accO[qf][df] = mfma16x16(vf[df], pfrag[qf][kvf], accO[qf][df]);
      }
      __syncthreads();
    }

    // write out: O^T regs -> attnOut [B*L][1024]; d = df*16+4g+r contiguous -> 8B stores
    for (int qf = 0; qf < 2; qf++) {
      float inv = 1.0f / lrun[qf];
      int q = qw + qf * 16 + c0;
      for (int df = 0; df < 4; df++) {
        ushort4 o;
        o.x = f2bf(accO[qf][df][0] * inv);
        o.y = f2bf(accO[qf][df][1] * inv);
        o.z = f2bf(accO[qf][df][2] * inv);
        o.w = f2bf(accO[qf][df][3] * inv);
        int d = df * 16 + 4 * g;
        *(ushort4*)&attnOut[(size_t)(bb * 2048 + q) * 1024 + h * 64 + d] = o;
      }
    }
  }
}

// ---------------- launch ----------------

extern "C" void kernel_launch(void* const* d_in, const int* in_sizes, int n_in,
                              void* d_out, int out_size, void* d_ws, size_t ws_size,
                              hipStream_t stream) {
  const float* x      = (const float*)d_in[0];
  const float* qkv_w  = (const float*)d_in[1];
  const float* qkv_b  = (const float*)d_in[2];
  const float* proj_w = (const float*)d_in[3];
  const float* proj_b = (const float*)d_in[4];
  float* out = (float*)d_out;

  char* ws = (char*)d_ws;
  u16* xb      = (u16*)ws;  ws += (size_t)8192 * 1024 * 2;
  u16* wqkvT   = (u16*)ws;  ws += (size_t)3072 * 1024 * 2;
  u16* wprojT  = (u16*)ws;  ws += (size_t)1024 * 1024 * 2;
  float* cosT  = (float*)ws; ws += (size_t)2048 * 32 * 4;
  float* sinT  = (float*)ws; ws += (size_t)2048 * 32 * 4;
  u16* Qb      = (u16*)ws;  ws += (size_t)64 * 2048 * 64 * 2;
  u16* Kb      = (u16*)ws;  ws += (size_t)64 * 2048 * 64 * 2;
  u16* Vt      = (u16*)ws;  ws += (size_t)64 * 2048 * 64 * 2;
  u16* attnOut = (u16*)ws;  ws += (size_t)8192 * 1024 * 2;
  // total ws usage ~92.3 MB

  convert_bf16_k<<<8192, 256, 0, stream>>>(x, xb, 8192 * 1024 / 4);
  {
    dim3 tg(16, 48);
    transpose_bf16_k<<<tg, 256, 0, stream>>>(qkv_w, wqkvT, 1024, 3072);
  }
  {
    dim3 tg(16, 16);
    transpose_bf16_k<<<tg, 256, 0, stream>>>(proj_w, wprojT, 1024, 1024);
  }
  rope_tables_k<<<256, 256, 0, stream>>>(cosT, sinT);

  // QKV: 8192x3072x1024, BM=256 BN=256 -> 32x12 = 384 blocks (%8==0)
  gemm8p<256, 1><<<384, 512, 0, stream>>>(xb, wqkvT, qkv_b, nullptr,
                                          Qb, Kb, Vt, cosT, sinT, 8192, 3072, 1024);
  attn_fwd<<<512, 256, 0, stream>>>(Qb, Kb, Vt, attnOut);
  // proj: 8192x1024x1024, BM=256 BN=128 -> 32x8 = 256 blocks (exactly 1/CU)
  gemm8p<128, 0><<<256, 512, 0, stream>>>(attnOut, wprojT, proj_b, out,
                                          nullptr, nullptr, nullptr, nullptr, nullptr,
                                          8192, 1024, 1024);
}

// Round 4
// 230.132 us; speedup vs baseline: 1.0556x; 1.0556x over previous
//
#include <hip/hip_runtime.h>
#include <hip/hip_bf16.h>
#include <math.h>

// Problem constants: B=4, L=2048, D=1024, H=16, hd=64
// M = B*L = 8192, QKV N = 3072, proj N = 1024, K = 1024

typedef unsigned short u16;
typedef __attribute__((ext_vector_type(8))) short bf8;   // 8 bf16 = 4 VGPR (MFMA A/B frag, K=32)
typedef __attribute__((ext_vector_type(4))) short bf4;   // 4 bf16 = 2 VGPR (MFMA A/B frag, K=16)
typedef __attribute__((ext_vector_type(4))) float f4;    // MFMA C/D frag

__device__ __forceinline__ u16 f2bf(float f) {
  unsigned int u = __float_as_uint(f);
  unsigned int r = (u + 0x7fffu + ((u >> 16) & 1u)) >> 16;
  return (u16)r;
}

__device__ __forceinline__ f4 mfma16(bf8 a, bf8 b, f4 c) {
  return __builtin_amdgcn_mfma_f32_16x16x32_bf16(a, b, c, 0, 0, 0);
}

__device__ __forceinline__ f4 mfma16x16(bf4 a, bf4 b, f4 c) {
#if __has_builtin(__builtin_amdgcn_mfma_f32_16x16x16bf16_1k)
  return __builtin_amdgcn_mfma_f32_16x16x16bf16_1k(a, b, c, 0, 0, 0);
#elif __has_builtin(__builtin_amdgcn_mfma_f32_16x16x16_bf16)
  return __builtin_amdgcn_mfma_f32_16x16x16_bf16(a, b, c, 0, 0, 0);
#else
  f4 d;
  asm volatile("v_mfma_f32_16x16x16_bf16 %0, %1, %2, %3"
               : "=v"(d) : "v"(a), "v"(b), "v"(c));
  return d;
#endif
}

__device__ __forceinline__ float fexp2(float x) {
#if __has_builtin(__builtin_amdgcn_exp2f)
  return __builtin_amdgcn_exp2f(x);
#else
  return exp2f(x);
#endif
}

__device__ __forceinline__ void async_copy16(const void* gsrc, void* ldst) {
  __builtin_amdgcn_global_load_lds(
      (__attribute__((address_space(1))) void*)gsrc,
      (__attribute__((address_space(3))) void*)ldst,
      16, 0, 0);
}

// ---------------- prep kernels ----------------

__global__ __launch_bounds__(256) void convert_bf16_k(const float* __restrict__ in,
                                                      u16* __restrict__ out, int n4) {
  int i = blockIdx.x * blockDim.x + threadIdx.x;
  if (i < n4) {
    float4 v = ((const float4*)in)[i];
    ushort4 o;
    o.x = f2bf(v.x); o.y = f2bf(v.y); o.z = f2bf(v.z); o.w = f2bf(v.w);
    ((ushort4*)out)[i] = o;
  }
}

// in [K][N] f32 row-major -> out [N][K] bf16 row-major (B^T layout). 64x64 tiles.
__global__ __launch_bounds__(256) void transpose_bf16_k(const float* __restrict__ in,
                                                        u16* __restrict__ out, int K, int N) {
  __shared__ float t[64][65];
  int k0 = blockIdx.x * 64;
  int n0 = blockIdx.y * 64;
  int tx = threadIdx.x & 63, ty = threadIdx.x >> 6;  // 4 rows per pass
  for (int i = 0; i < 16; i++) {
    int r = ty + i * 4;
    t[r][tx] = in[(size_t)(k0 + r) * N + n0 + tx];
  }
  __syncthreads();
  for (int i = 0; i < 16; i++) {
    int r = ty + i * 4;
    out[(size_t)(n0 + r) * K + k0 + tx] = f2bf(t[tx][r]);
  }
}

// cos/sin tables [2048][32] f32
__global__ __launch_bounds__(256) void rope_tables_k(float* __restrict__ cosT,
                                                     float* __restrict__ sinT) {
  int i = blockIdx.x * blockDim.x + threadIdx.x;  // 65536
  int l = i >> 5, j = i & 31;
  float inv = powf(10000.0f, -(float)j / 32.0f);
  float f = (float)l * inv;
  cosT[i] = cosf(f);
  sinT[i] = sinf(f);
}

// ---------------- pipelined GEMM (A[M][K]bf16 x Bt[N][K]bf16) ----------------
// BM=128, BN=256, BK=64. 512 threads = 8 waves (2M x 4N); per-wave 64x64 = acc[4][4].
// 3 LDS buffers (144 KiB), stage lag 2: during tile kt's phases stage tile kt+2 into
// buf[(kt+2)%3] -- never the buffer being read. Per phase (one ks-half of the K-tile):
// {8 ds_read_b128, 3 stage gloads, s_barrier, setprio(1), 16 MFMA, setprio(0), s_barrier}.
// Counted vmcnt(6) once per K-tile (drains exactly tile kt+1), never 0 mid-loop; raw
// s_barrier everywhere so the compiler never drains vmcnt.
// LDS rows are 128 B; swizzle cb ^= ((row&7)<<4) on BOTH the pre-swizzled global source
// (global_load_lds writes linearly) and the ds_read address.
// EPI==0: out f32 += bias. EPI==1: fused bias+RoPE -> Qb/Kb [bh][l][64], Vt [bh][64][l].

template <int EPI>
__global__ __launch_bounds__(512, 1) void gemm_p3(
    const u16* __restrict__ A, const u16* __restrict__ Bt, const float* __restrict__ bias,
    float* __restrict__ outF,
    u16* __restrict__ Qb, u16* __restrict__ Kb, u16* __restrict__ Vt,
    const float* __restrict__ cosT, const float* __restrict__ sinT,
    int M, int N, int K) {
  constexpr int BM = 128, BN = 256;
  constexpr int TILE_U16 = (BM + BN) * 64;      // 24576 u16 = 48 KB
  __shared__ __attribute__((aligned(16))) u16 lds[3 * TILE_U16];

  const int tid = threadIdx.x;
  const int lane = tid & 63, wid = tid >> 6;
  const int nbn = N / BN;
  const int cpx = gridDim.x >> 3;               // grid % 8 == 0 by construction
  const int bid = ((int)blockIdx.x % 8) * cpx + ((int)blockIdx.x >> 3);
  const int bm = bid / nbn, bn = bid % nbn;
  const int m0 = bm * BM, n0 = bn * BN;
  const int wm = wid >> 2, wn = wid & 3;        // 2 x 4 waves, per-wave 64x64
  const int g = lane >> 4, c0 = lane & 15;
  const int NT = K >> 6;                        // 16 K-tiles of BK=64

  // stage 3 of the 6 per-thread loads of tile kt into buffer buf (s0 = 0 or 3)
  auto stage3 = [&](int kt, int buf, int s0) {
#pragma unroll
    for (int s = 0; s < 3; ++s) {
      int off = (s0 + s) * 8192 + tid * 16;     // linear LDS byte offset in tile
      char* dst = (char*)lds + (size_t)buf * (TILE_U16 * 2) + off;
      int row, chunk;
      const u16* gb;
      if (off < BM * 128) {                     // A region: [128][64] u16
        row = off >> 7; chunk = (off >> 4) & 7;
        gb = A + (size_t)(m0 + row) * K;
      } else {                                  // B region: [256][64] u16
        int bo = off - BM * 128;
        row = bo >> 7; chunk = (bo >> 4) & 7;
        gb = Bt + (size_t)(n0 + row) * K;
      }
      async_copy16((const char*)(gb + (kt << 6)) + ((chunk ^ (row & 7)) << 4), dst);
    }
  };
  auto rd = [&](const u16* base, int row, int ks) -> bf8 {
    int cb = (ks * 64 + g * 16) ^ ((row & 7) << 4);
    return *(const bf8*)((const char*)base + row * 128 + cb);
  };

  f4 acc[4][4];
#pragma unroll
  for (int i = 0; i < 4; i++)
#pragma unroll
    for (int j = 0; j < 4; j++) acc[i][j] = (f4)0.0f;

  // prologue: tiles 0,1 staged; counted wait for tile 0 (6 younger = tile 1)
  stage3(0, 0, 0); stage3(0, 0, 3);
  stage3(1, 1, 0); stage3(1, 1, 3);
  asm volatile("s_waitcnt vmcnt(6)" ::: "memory");
  __builtin_amdgcn_s_barrier();

  for (int kt = 0; kt < NT; ++kt) {
    const u16* bufA = lds + (kt % 3) * TILE_U16;
    const u16* bufB = bufA + BM * 64;
    const int nbuf = (kt + 2) % 3;
    const bool pf = (kt + 2 < NT);

#pragma unroll
    for (int ph = 0; ph < 2; ++ph) {
      if (pf) stage3(kt + 2, nbuf, ph * 3);
      bf8 av[4], bv[4];
#pragma unroll
      for (int nf = 0; nf < 4; nf++) bv[nf] = rd(bufB, wn * 64 + nf * 16 + c0, ph);
#pragma unroll
      for (int mf = 0; mf < 4; mf++) av[mf] = rd(bufA, wm * 64 + mf * 16 + c0, ph);
      __builtin_amdgcn_s_barrier();
      __builtin_amdgcn_s_setprio(1);
#pragma unroll
      for (int mf = 0; mf < 4; mf++)
#pragma unroll
        for (int nf = 0; nf < 4; nf++)
          acc[mf][nf] = mfma16(av[mf], bv[nf], acc[mf][nf]);
      __builtin_amdgcn_s_setprio(0);
      if (ph == 1) {
        if (kt + 2 < NT)      asm volatile("s_waitcnt vmcnt(6)" ::: "memory");
        else if (kt + 1 < NT) asm volatile("s_waitcnt vmcnt(0)" ::: "memory");
      }
      if (!(kt == NT - 1 && ph == 1)) __builtin_amdgcn_s_barrier();
    }
  }

  // ---- epilogue ----  col = n0 + wn*64 + nf*16 + c0; row = m0 + wm*64 + mf*16 + g*4 + r
  if (EPI == 0) {
#pragma unroll
    for (int nf = 0; nf < 4; nf++) {
      int col = n0 + wn * 64 + nf * 16 + c0;
      float bv = bias[col];
#pragma unroll
      for (int mf = 0; mf < 4; mf++) {
        int rowb = m0 + wm * 64 + mf * 16 + g * 4;
#pragma unroll
        for (int r = 0; r < 4; r++)
          outF[(size_t)(rowb + r) * N + col] = acc[mf][nf][r] + bv;
      }
    }
  } else {
#pragma unroll
    for (int nf = 0; nf < 4; nf++) {
      int col = n0 + wn * 64 + nf * 16 + c0;
      int sec = col >> 10;          // 0=q 1=k 2=v
      int hc = col & 1023;
      int h = hc >> 6, d = hc & 63;
      float bv = bias[col];
      float pbv = bias[n0 + wn * 64 + (nf ^ 2) * 16 + c0];  // RoPE partner (d +/- 32)
#pragma unroll
      for (int mf = 0; mf < 4; mf++) {
        int rowb = m0 + wm * 64 + mf * 16 + g * 4;
#pragma unroll
        for (int r = 0; r < 4; r++) {
          int row = rowb + r;
          int bb = row >> 11, l = row & 2047;
          int bh = bb * 16 + h;
          float v = acc[mf][nf][r] + bv;
          if (sec == 2) {
            Vt[((size_t)bh * 64 + d) * 2048 + l] = f2bf(v);  // V stored transposed [bh][d][l]
          } else {
            int dm = d & 31;
            float cz = cosT[l * 32 + dm], sz = sinT[l * 32 + dm];
            float pv = acc[mf][nf ^ 2][r] + pbv;
            float o = (d < 32) ? (v * cz - pv * sz) : (v * cz + pv * sz);
            u16* dst = (sec == 0) ? Qb : Kb;
            dst[((size_t)bh * 2048 + l) * 64 + d] = f2bf(o);
          }
        }
      }
    }
  }
}

// ---------------- flash attention (swapped-operand, balanced pairs) ----------------
// 512 blocks = 64 bh x 8 q-tile-pairs; block handles q-tiles (pi) and (15-pi): exactly
// 34 KV-tiles of work each -> perfectly balanced, all blocks co-resident (2/CU).
// 4 waves x 32 q rows. KV tile 64. S^T = mfma(K, Q): lane owns one q-row (q=col=c0);
// softmax is lane-local + 2 shfl_xor; P is *already* the 16x16x16 PV B-fragment
// (k = 4g + r) -> no LDS round-trip, no cross-lane P movement.
// K/V double-buffered in LDS via global_load_lds with XOR-swizzled source.
__global__ __launch_bounds__(256, 2) void attn_fwd(
    const u16* __restrict__ Qb, const u16* __restrict__ Kb, const u16* __restrict__ Vt,
    u16* __restrict__ attnOut) {
  __shared__ __attribute__((aligned(16))) u16 kT[2][64 * 64];
  __shared__ __attribute__((aligned(16))) u16 vT[2][64 * 64];
  const int tid = threadIdx.x, lane = tid & 63, wid = tid >> 6;
  // XCD swizzle: 8 blocks sharing one bh land on one XCD (K/V 4MB/XCD = L2-fit)
  const int pblk = blockIdx.x;                 // nwg = 512
  const int lblk = ((pblk & 7) << 6) | (pblk >> 3);
  const int bh = lblk >> 3, pi = lblk & 7;
  const int bb = bh >> 4, h = bh & 15;
  const u16* Qp = Qb + (size_t)bh * 2048 * 64;
  const u16* Kp = Kb + (size_t)bh * 2048 * 64;
  const u16* Vp = Vt + (size_t)bh * 64 * 2048;   // [64 d][2048 l]
  const int g = lane >> 4, c0 = lane & 15;
  const float sc = 0.125f * 1.4426950408889634f;  // scale * log2(e)

  auto stage = [&](int kt, int buf) {
    int kv0 = kt * 64;
    for (int i = 0; i < 2; i++) {
      int chunk = i * 4 + wid;
      int p = chunk * 1024 + lane * 16;
      int row = p >> 7, pb = p & 127;
      int lb = pb ^ ((row & 7) << 4);
      async_copy16((const char*)(Kp + (size_t)(kv0 + row) * 64) + lb,
                   (char*)kT[buf] + chunk * 1024);
      async_copy16((const char*)(Vp + (size_t)row * 2048 + kv0) + lb,
                   (char*)vT[buf] + chunk * 1024);
    }
  };

  for (int seg = 0; seg < 2; ++seg) {
    const int qt = seg ? (15 - pi) : pi;
    const int q0 = qt << 7;
    const int qw = q0 + wid * 32;

    // Q B-fragments hoisted (n = q = c0, k = d contiguous)
    bf8 qfr[2][2];
    for (int qf = 0; qf < 2; qf++)
      for (int ks = 0; ks < 2; ks++)
        qfr[qf][ks] = *(const bf8*)((const char*)Qp +
                                    (size_t)(qw + qf * 16 + c0) * 128 + ks * 64 + g * 16);

    f4 accO[2][4];
    for (int i = 0; i < 2; i++)
      for (int j = 0; j < 4; j++) accO[i][j] = (f4)0.0f;
    float mrun[2] = {-INFINITY, -INFINITY}, lrun[2] = {0.f, 0.f};

    const int nkt = (q0 >> 6) + 2;
    stage(0, 0);
    __syncthreads();

    for (int kt = 0; kt < nkt; ++kt) {
      const int cur = kt & 1;
      if (kt + 1 < nkt) stage(kt + 1, cur ^ 1);
      const char* kbuf = (const char*)kT[cur];
      const char* vbuf = (const char*)vT[cur];
      const int kv0 = kt * 64;

      // S^T = K Q^T  (m = kv, n = q)
      f4 s[2][4];
      for (int i = 0; i < 2; i++)
        for (int j = 0; j < 4; j++) s[i][j] = (f4)0.0f;
      bf8 kf[4][2];
      for (int ks = 0; ks < 2; ks++) {
        int cb = ks * 64 + g * 16;
        for (int kvf = 0; kvf < 4; kvf++) {
          int row = kvf * 16 + c0;
          kf[kvf][ks] = *(const bf8*)(kbuf + (row << 7) + (cb ^ ((row & 7) << 4)));
        }
      }
      for (int ks = 0; ks < 2; ks++)
        for (int kvf = 0; kvf < 4; kvf++)
          for (int qf = 0; qf < 2; qf++)
            s[qf][kvf] = mfma16(kf[kvf][ks], qfr[qf][ks], s[qf][kvf]);

      // scale to log2 domain + causal mask (q = qw+qf*16+c0, kv = kv0+kvf*16+4g+r)
      for (int qf = 0; qf < 2; qf++) {
        int q = qw + qf * 16 + c0;
        for (int kvf = 0; kvf < 4; kvf++)
          for (int r = 0; r < 4; r++) {
            int kv = kv0 + kvf * 16 + 4 * g + r;
            float v = s[qf][kvf][r] * sc;
            s[qf][kvf][r] = (kv > q) ? -INFINITY : v;
          }
      }

      // online softmax: lane-local reduce + 2 shfl_xor across the 4 g-groups
      bf4 pfrag[2][4];
      float pc[2];
      for (int qf = 0; qf < 2; qf++) {
        float mx = s[qf][0][0];
        for (int kvf = 0; kvf < 4; kvf++)
          for (int r = 0; r < 4; r++) mx = fmaxf(mx, s[qf][kvf][r]);
        mx = fmaxf(mx, __shfl_xor(mx, 16));
        mx = fmaxf(mx, __shfl_xor(mx, 32));
        float mn = fmaxf(mrun[qf], mx);
        pc[qf] = fexp2(mrun[qf] - mn);
        float ls = 0.f;
        for (int kvf = 0; kvf < 4; kvf++) {
          bf4 pf;
          for (int r = 0; r < 4; r++) {
            float pv = fexp2(s[qf][kvf][r] - mn);
            ls += pv;
            pf[r] = (short)f2bf(pv);
          }
          pfrag[qf][kvf] = pf;
        }
        ls += __shfl_xor(ls, 16);
        ls += __shfl_xor(ls, 32);
        lrun[qf] = lrun[qf] * pc[qf] + ls;
        mrun[qf] = mn;
      }

      // rescale O
      for (int qf = 0; qf < 2; qf++)
        for (int df = 0; df < 4; df++)
          for (int r = 0; r < 4; r++) accO[qf][df][r] *= pc[qf];

      // O^T += V^T P^T  via 16x16x16 (A = V^T rows d, B = P fragment direct from regs)
      for (int kvf = 0; kvf < 4; kvf++) {
        bf4 vf[4];
        int cb = kvf * 32 + g * 8;
        for (int df = 0; df < 4; df++) {
          int row = df * 16 + c0;
          vf[df] = *(const bf4*)(vbuf + (row << 7) + (cb ^ ((row & 7) << 4)));
        }
        for (int df = 0; df < 4; df++)
          for (int qf = 0; qf < 2; qf++)
            accO[qf][df] = mfma16x16(vf[df], pfrag[qf][kvf], accO[qf][df]);
      }
      __syncthreads();
    }

    // write out: O^T regs -> attnOut [B*L][1024]; d = df*16+4g+r contiguous -> 8B stores
    for (int qf = 0; qf < 2; qf++) {
      float inv = 1.0f / lrun[qf];
      int q = qw + qf * 16 + c0;
      for (int df = 0; df < 4; df++) {
        ushort4 o;
        o.x = f2bf(accO[qf][df][0] * inv);
        o.y = f2bf(accO[qf][df][1] * inv);
        o.z = f2bf(accO[qf][df][2] * inv);
        o.w = f2bf(accO[qf][df][3] * inv);
        int d = df * 16 + 4 * g;
        *(ushort4*)&attnOut[(size_t)(bb * 2048 + q) * 1024 + h * 64 + d] = o;
      }
    }
  }
}

// ---------------- launch ----------------

extern "C" void kernel_launch(void* const* d_in, const int* in_sizes, int n_in,
                              void* d_out, int out_size, void* d_ws, size_t ws_size,
                              hipStream_t stream) {
  const float* x      = (const float*)d_in[0];
  const float* qkv_w  = (const float*)d_in[1];
  const float* qkv_b  = (const float*)d_in[2];
  const float* proj_w = (const float*)d_in[3];
  const float* proj_b = (const float*)d_in[4];
  float* out = (float*)d_out;

  char* ws = (char*)d_ws;
  u16* xb      = (u16*)ws;  ws += (size_t)8192 * 1024 * 2;
  u16* wqkvT   = (u16*)ws;  ws += (size_t)3072 * 1024 * 2;
  u16* wprojT  = (u16*)ws;  ws += (size_t)1024 * 1024 * 2;
  float* cosT  = (float*)ws; ws += (size_t)2048 * 32 * 4;
  float* sinT  = (float*)ws; ws += (size_t)2048 * 32 * 4;
  u16* Qb      = (u16*)ws;  ws += (size_t)64 * 2048 * 64 * 2;
  u16* Kb      = (u16*)ws;  ws += (size_t)64 * 2048 * 64 * 2;
  u16* Vt      = (u16*)ws;  ws += (size_t)64 * 2048 * 64 * 2;
  u16* attnOut = (u16*)ws;  ws += (size_t)8192 * 1024 * 2;
  // total ws usage ~92.3 MB

  convert_bf16_k<<<8192, 256, 0, stream>>>(x, xb, 8192 * 1024 / 4);
  {
    dim3 tg(16, 48);
    transpose_bf16_k<<<tg, 256, 0, stream>>>(qkv_w, wqkvT, 1024, 3072);
  }
  {
    dim3 tg(16, 16);
    transpose_bf16_k<<<tg, 256, 0, stream>>>(proj_w, wprojT, 1024, 1024);
  }
  rope_tables_k<<<256, 256, 0, stream>>>(cosT, sinT);

  // QKV: 8192x3072x1024, BM=128 BN=256 -> 64x12 = 768 blocks = exactly 3 rounds @1/CU
  gemm_p3<1><<<768, 512, 0, stream>>>(xb, wqkvT, qkv_b, nullptr,
                                      Qb, Kb, Vt, cosT, sinT, 8192, 3072, 1024);
  attn_fwd<<<512, 256, 0, stream>>>(Qb, Kb, Vt, attnOut);
  // proj: 8192x1024x1024, BM=128 BN=256 -> 64x4 = 256 blocks = exactly 1 round @1/CU
  gemm_p3<0><<<256, 512, 0, stream>>>(attnOut, wprojT, proj_b, out,
                                      nullptr, nullptr, nullptr, nullptr, nullptr,
                                      8192, 1024, 1024);
}